// Round 1
// baseline (123.183 us; speedup 1.0000x reference)
//
#include <hip/hip_runtime.h>
#include <hip/hip_bf16.h>

#define H_NUM 16
#define S_LEN 2048
#define D_DIM 128
#define WIN   512

typedef __attribute__((ext_vector_type(8))) short short8;
typedef __attribute__((ext_vector_type(4))) float f32x4;

static __device__ __forceinline__ unsigned short bf_rne(float f) {
    unsigned u = __builtin_bit_cast(unsigned, f);
    u = (u + 0x7FFFu + ((u >> 16) & 1u)) >> 16;
    return (unsigned short)u;
}
static __device__ __forceinline__ float bf_f(unsigned short b) {
    unsigned u = ((unsigned)b) << 16;
    return __builtin_bit_cast(float, u);
}

// One wave (64 threads) per (head, 16-query tile). Flash-style sliding window.
// S accumulator layout (16x16x32 bf16 MFMA, m89-verified):
//   C/D: col = lane&15, row = (lane>>4)*4 + reg
//   A:   row = lane&15, k = (lane>>4)*8 + e
//   B:   col = lane&15, k = (lane>>4)*8 + e
__global__ __launch_bounds__(64) void swa_fwd(
    const float* __restrict__ Q, const float* __restrict__ K,
    const float* __restrict__ V, float* __restrict__ O)
{
    __shared__ short p_lds[16][40];   // 16 q-rows x 32 keys, padded to 40 (bank-spread)

    // XCD-bijective swizzle: 2048 WGs = 8 XCDs x 256. Each XCD owns 2 whole heads
    // -> 4 MB K/V working set ~= its private L2.
    int bid = blockIdx.x;
    int wid = ((bid & 7) << 8) | (bid >> 3);
    int h   = wid >> 7;          // head
    int qt  = wid & 127;         // q-tile
    int q0  = qt << 4;

    int lane = threadIdx.x;
    int lo = lane & 15;
    int g  = lane >> 4;

    const float* Qh = Q + ((size_t)h << 18);   // h*S*D = h*2048*128
    const float* Kh = K + ((size_t)h << 18);
    const float* Vh = V + ((size_t)h << 18);
    float*       Oh = O + ((size_t)h << 18);

    // ---- Load Q fragments once, split into hi/lo bf16 (fp32-accurate QK^T) ----
    short8 qa_h[4], qa_l[4];
    const float* qrow = Qh + ((size_t)(q0 + lo) << 7) + g * 8;
    #pragma unroll
    for (int c = 0; c < 4; ++c) {
        float4 a0 = *reinterpret_cast<const float4*>(qrow + c * 32);
        float4 a1 = *reinterpret_cast<const float4*>(qrow + c * 32 + 4);
        float xs[8] = {a0.x, a0.y, a0.z, a0.w, a1.x, a1.y, a1.z, a1.w};
        #pragma unroll
        for (int e = 0; e < 8; ++e) {
            unsigned short hh = bf_rne(xs[e]);
            float hf = bf_f(hh);
            unsigned short ll = bf_rne(xs[e] - hf);
            qa_h[c][e] = (short)hh;
            qa_l[c][e] = (short)ll;
        }
    }

    f32x4 oacc[8];
    #pragma unroll
    for (int dc = 0; dc < 8; ++dc) oacc[dc] = (f32x4){0.f, 0.f, 0.f, 0.f};
    float m_r[4], l_r[4];
    #pragma unroll
    for (int r = 0; r < 4; ++r) { m_r[r] = -1e30f; l_r[r] = 0.f; }

    int kstart = q0 - (WIN - 1); if (kstart < 0) kstart = 0;
    int kend   = q0 + 16;

    for (int kb = kstart; kb < kend; kb += 32) {
        // ---------------- QK^T (split precision: qh*kh + qh*kl + ql*kh) ----------
        f32x4 sacc[2];
        sacc[0] = (f32x4){0.f,0.f,0.f,0.f};
        sacc[1] = (f32x4){0.f,0.f,0.f,0.f};
        #pragma unroll
        for (int kg = 0; kg < 2; ++kg) {
            int krow = kb + kg * 16 + lo;
            if (krow > S_LEN - 1) krow = S_LEN - 1;     // clamped rows are masked later
            const float* ksrc = Kh + ((size_t)krow << 7) + g * 8;
            #pragma unroll
            for (int c = 0; c < 4; ++c) {
                float4 b0 = *reinterpret_cast<const float4*>(ksrc + c * 32);
                float4 b1 = *reinterpret_cast<const float4*>(ksrc + c * 32 + 4);
                float xs[8] = {b0.x, b0.y, b0.z, b0.w, b1.x, b1.y, b1.z, b1.w};
                short8 kh8, kl8;
                #pragma unroll
                for (int e = 0; e < 8; ++e) {
                    unsigned short hh = bf_rne(xs[e]);
                    float hf = bf_f(hh);
                    unsigned short ll = bf_rne(xs[e] - hf);
                    kh8[e] = (short)hh;
                    kl8[e] = (short)ll;
                }
                sacc[kg] = __builtin_amdgcn_mfma_f32_16x16x32_bf16(qa_h[c], kh8, sacc[kg], 0, 0, 0);
                sacc[kg] = __builtin_amdgcn_mfma_f32_16x16x32_bf16(qa_h[c], kl8, sacc[kg], 0, 0, 0);
                sacc[kg] = __builtin_amdgcn_mfma_f32_16x16x32_bf16(qa_l[c], kh8, sacc[kg], 0, 0, 0);
            }
        }

        // ---------------- mask + online softmax ----------------
        float p0s[4], p1s[4];
        #pragma unroll
        for (int r = 0; r < 4; ++r) {
            int i_row = q0 + g * 4 + r;
            int j0 = kb + lo, j1 = kb + 16 + lo;
            float s0 = sacc[0][r], s1 = sacc[1][r];
            s0 = ((j0 <= i_row) && (j0 + WIN > i_row)) ? s0 : -1e30f;
            s1 = ((j1 <= i_row) && (j1 + WIN > i_row)) ? s1 : -1e30f;
            float tm = fmaxf(s0, s1);
            tm = fmaxf(tm, __shfl_xor(tm, 1));
            tm = fmaxf(tm, __shfl_xor(tm, 2));
            tm = fmaxf(tm, __shfl_xor(tm, 4));
            tm = fmaxf(tm, __shfl_xor(tm, 8));
            float mn = fmaxf(m_r[r], tm);
            float p0 = __expf(s0 - mn);
            float p1 = __expf(s1 - mn);
            float ts = p0 + p1;
            ts += __shfl_xor(ts, 1);
            ts += __shfl_xor(ts, 2);
            ts += __shfl_xor(ts, 4);
            ts += __shfl_xor(ts, 8);
            float scale = __expf(m_r[r] - mn);
            l_r[r] = l_r[r] * scale + ts;
            m_r[r] = mn;
            p0s[r] = p0; p1s[r] = p1;
            #pragma unroll
            for (int dc = 0; dc < 8; ++dc) oacc[dc][r] *= scale;
        }

        // ---------------- P -> LDS (redistribute to A-fragment layout) ----------
        #pragma unroll
        for (int r = 0; r < 4; ++r) {
            p_lds[g * 4 + r][lo]      = (short)bf_rne(p0s[r]);
            p_lds[g * 4 + r][16 + lo] = (short)bf_rne(p1s[r]);
        }
        // single wave: order ds_write -> ds_read (no barrier needed)
        asm volatile("s_waitcnt lgkmcnt(0)" ::: "memory");
        short8 pa = *reinterpret_cast<const short8*>(&p_lds[lo][g * 8]);

        // ---------------- P @ V (V read direct from global; L2-resident) --------
        const float* vrp[8];
        #pragma unroll
        for (int e = 0; e < 8; ++e) {
            int vrow = kb + g * 8 + e;
            if (vrow > S_LEN - 1) vrow = S_LEN - 1;     // p == 0 there
            vrp[e] = Vh + ((size_t)vrow << 7) + lo;
        }
        #pragma unroll
        for (int dc = 0; dc < 8; ++dc) {
            short8 vb;
            #pragma unroll
            for (int e = 0; e < 8; ++e)
                vb[e] = (short)bf_rne(vrp[e][dc * 16]);
            oacc[dc] = __builtin_amdgcn_mfma_f32_16x16x32_bf16(pa, vb, oacc[dc], 0, 0, 0);
        }
    }

    // ---------------- epilogue: divide by l, store ----------------
    #pragma unroll
    for (int r = 0; r < 4; ++r) {
        float inv = 1.0f / l_r[r];
        float* orow = Oh + ((size_t)(q0 + g * 4 + r) << 7) + lo;
        #pragma unroll
        for (int dc = 0; dc < 8; ++dc)
            orow[dc * 16] = oacc[dc][r] * inv;
    }
}

extern "C" void kernel_launch(void* const* d_in, const int* in_sizes, int n_in,
                              void* d_out, int out_size, void* d_ws, size_t ws_size,
                              hipStream_t stream) {
    (void)in_sizes; (void)n_in; (void)d_ws; (void)ws_size; (void)out_size;
    const float* q = (const float*)d_in[0];
    const float* k = (const float*)d_in[1];
    const float* v = (const float*)d_in[2];
    // d_in[3] = mask: structural (causal sliding window, W=512) — not read.
    float* o = (float*)d_out;
    dim3 grid(H_NUM * (S_LEN / 16));   // 2048 single-wave workgroups
    dim3 block(64);
    hipLaunchKernelGGL(swa_fwd, grid, block, 0, stream, q, k, v, o);
}

// Round 2
// 115.043 us; speedup vs baseline: 1.0708x; 1.0708x over previous
//
#include <hip/hip_runtime.h>
#include <hip/hip_bf16.h>

#define H_NUM 16
#define S_LEN 2048
#define D_DIM 128
#define WIN   512
#define HSD   (H_NUM * S_LEN * D_DIM)   // 4194304 elements

typedef __attribute__((ext_vector_type(8))) short short8;
typedef __attribute__((ext_vector_type(4))) short short4v;
typedef __attribute__((ext_vector_type(4))) float f32x4;

static __device__ __forceinline__ unsigned short bf_rne(float f) {
    unsigned u = __builtin_bit_cast(unsigned, f);
    u = (u + 0x7FFFu + ((u >> 16) & 1u)) >> 16;
    return (unsigned short)u;
}
static __device__ __forceinline__ float bf_f(unsigned short b) {
    unsigned u = ((unsigned)b) << 16;
    return __builtin_bit_cast(float, u);
}

// ---- pre-pass 1: split K into hi/lo bf16 (fp32-accurate QK^T operands) ----
__global__ __launch_bounds__(256) void split_k(
    const float* __restrict__ K, short* __restrict__ khi, short* __restrict__ klo)
{
    size_t i = ((size_t)blockIdx.x * 256 + threadIdx.x) * 4;
    float4 x = *reinterpret_cast<const float4*>(K + i);
    float xs[4] = {x.x, x.y, x.z, x.w};
    short4v h4, l4;
    #pragma unroll
    for (int e = 0; e < 4; ++e) {
        unsigned short hh = bf_rne(xs[e]);
        h4[e] = (short)hh;
        l4[e] = (short)bf_rne(xs[e] - bf_f(hh));
    }
    *reinterpret_cast<short4v*>(khi + i) = h4;
    *reinterpret_cast<short4v*>(klo + i) = l4;
}

// ---- pre-pass 2: V [h][s][d] fp32 -> Vt [h][d][s] bf16 (32x32 LDS tiles) ----
__global__ __launch_bounds__(256) void vtrans(
    const float* __restrict__ V, short* __restrict__ vt)
{
    __shared__ short t[32][33];
    int h = blockIdx.z, s0 = blockIdx.x * 32, d0 = blockIdx.y * 32;
    int tid = threadIdx.x;
    int r = tid >> 3;          // 0..31
    int c = (tid & 7) * 4;     // 0,4,...,28
    float4 x = *reinterpret_cast<const float4*>(
        V + ((size_t)(h * S_LEN + s0 + r) << 7) + d0 + c);
    t[r][c + 0] = (short)bf_rne(x.x);
    t[r][c + 1] = (short)bf_rne(x.y);
    t[r][c + 2] = (short)bf_rne(x.z);
    t[r][c + 3] = (short)bf_rne(x.w);
    __syncthreads();
    short4v y;
    #pragma unroll
    for (int e = 0; e < 4; ++e) y[e] = t[c + e][r];   // Vt[d0+r][s0+c+e] = V[s0+c+e][d0+r]
    *reinterpret_cast<short4v*>(vt + (size_t)(h * D_DIM + d0 + r) * S_LEN + s0 + c) = y;
}

// ---- main: flash SWA, 2 waves per WG (KV-split), 16 q-rows per WG ----
// MFMA 16x16x32 bf16 layouts (m89-verified):
//   A: row=lane&15, k=(lane>>4)*8+e   B: col=lane&15, k=(lane>>4)*8+e
//   C/D: col=lane&15, row=(lane>>4)*4+reg
__global__ __launch_bounds__(128, 4) void swa_fwd(
    const float* __restrict__ Q, const short* __restrict__ khi,
    const short* __restrict__ klo, const short* __restrict__ vt,
    float* __restrict__ O)
{
    __shared__ short p_lds[2][16][40];   // per-wave P redistribution buffer
    __shared__ float m_o[64][36];        // wave1 O-partial (padded: bank-spread)
    __shared__ float m_ml[64][8];        // wave1 m/l partials

    // XCD-bijective swizzle (2048 % 8 == 0): each XCD owns 2 whole heads.
    int bid = blockIdx.x;
    int wid = ((bid & 7) << 8) | (bid >> 3);
    int h   = wid >> 7;
    int qt  = wid & 127;
    int q0  = qt << 4;

    int tid  = threadIdx.x;
    int wave = tid >> 6;
    int lane = tid & 63;
    int lo = lane & 15;
    int g  = lane >> 4;

    const float* Qh = Q   + ((size_t)h << 18);
    const short* Kh = khi + ((size_t)h << 18);
    const short* Lh = klo + ((size_t)h << 18);
    const short* Vh = vt  + ((size_t)h << 18);
    float*       Oh = O   + ((size_t)h << 18);

    // Q fragments, split hi/lo bf16 (once per wave; not redundant across tiles)
    short8 qa_h[4], qa_l[4];
    const float* qrow = Qh + ((size_t)(q0 + lo) << 7) + g * 8;
    #pragma unroll
    for (int c = 0; c < 4; ++c) {
        float4 a0 = *reinterpret_cast<const float4*>(qrow + c * 32);
        float4 a1 = *reinterpret_cast<const float4*>(qrow + c * 32 + 4);
        float xs[8] = {a0.x, a0.y, a0.z, a0.w, a1.x, a1.y, a1.z, a1.w};
        #pragma unroll
        for (int e = 0; e < 8; ++e) {
            unsigned short hh = bf_rne(xs[e]);
            qa_h[c][e] = (short)hh;
            qa_l[c][e] = (short)bf_rne(xs[e] - bf_f(hh));
        }
    }

    f32x4 oacc[8];
    #pragma unroll
    for (int dc = 0; dc < 8; ++dc) oacc[dc] = (f32x4){0.f, 0.f, 0.f, 0.f};
    float m_r[4], l_r[4];
    #pragma unroll
    for (int r = 0; r < 4; ++r) { m_r[r] = -1e30f; l_r[r] = 0.f; }

    int kstart = q0 - (WIN - 1);
    if (kstart < 0) kstart = 0;
    kstart &= ~31;                      // 32-align: keeps bf16 loads 16B-aligned
    int kend = q0 + 16;
    int nt   = (kend - kstart + 31) >> 5;
    int nt0  = (nt + 1) >> 1;
    int tb = (wave == 0) ? 0   : nt0;
    int te = (wave == 0) ? nt0 : nt;

    for (int ti = tb; ti < te; ++ti) {
        int kb = kstart + ti * 32;

        // -------- QK^T: qh*kh + qh*kl + ql*kh --------
        f32x4 sacc[2];
        sacc[0] = (f32x4){0.f,0.f,0.f,0.f};
        sacc[1] = (f32x4){0.f,0.f,0.f,0.f};
        #pragma unroll
        for (int kg = 0; kg < 2; ++kg) {
            int krow = kb + kg * 16 + lo;
            if (krow > S_LEN - 1) krow = S_LEN - 1;   // masked later
            const short* khp = Kh + ((size_t)krow << 7) + g * 8;
            const short* klp = Lh + ((size_t)krow << 7) + g * 8;
            #pragma unroll
            for (int c = 0; c < 4; ++c) {
                short8 kh8 = *reinterpret_cast<const short8*>(khp + c * 32);
                short8 kl8 = *reinterpret_cast<const short8*>(klp + c * 32);
                sacc[kg] = __builtin_amdgcn_mfma_f32_16x16x32_bf16(qa_h[c], kh8, sacc[kg], 0, 0, 0);
                sacc[kg] = __builtin_amdgcn_mfma_f32_16x16x32_bf16(qa_h[c], kl8, sacc[kg], 0, 0, 0);
                sacc[kg] = __builtin_amdgcn_mfma_f32_16x16x32_bf16(qa_l[c], kh8, sacc[kg], 0, 0, 0);
            }
        }

        // -------- mask + online softmax --------
        float p0s[4], p1s[4];
        #pragma unroll
        for (int r = 0; r < 4; ++r) {
            int i_row = q0 + g * 4 + r;
            int j0 = kb + lo, j1 = kb + 16 + lo;
            float s0 = sacc[0][r], s1 = sacc[1][r];
            s0 = ((j0 <= i_row) && (j0 + WIN > i_row)) ? s0 : -1e30f;
            s1 = ((j1 <= i_row) && (j1 + WIN > i_row)) ? s1 : -1e30f;
            float tm = fmaxf(s0, s1);
            tm = fmaxf(tm, __shfl_xor(tm, 1));
            tm = fmaxf(tm, __shfl_xor(tm, 2));
            tm = fmaxf(tm, __shfl_xor(tm, 4));
            tm = fmaxf(tm, __shfl_xor(tm, 8));
            float mn = fmaxf(m_r[r], tm);
            float p0 = __expf(s0 - mn);
            float p1 = __expf(s1 - mn);
            float ts = p0 + p1;
            ts += __shfl_xor(ts, 1);
            ts += __shfl_xor(ts, 2);
            ts += __shfl_xor(ts, 4);
            ts += __shfl_xor(ts, 8);
            float scale = __expf(m_r[r] - mn);
            l_r[r] = l_r[r] * scale + ts;
            m_r[r] = mn;
            p0s[r] = p0; p1s[r] = p1;
            #pragma unroll
            for (int dc = 0; dc < 8; ++dc) oacc[dc][r] *= scale;
        }

        // -------- P -> LDS (redistribute to A-fragment layout) --------
        #pragma unroll
        for (int r = 0; r < 4; ++r) {
            p_lds[wave][g * 4 + r][lo]      = (short)bf_rne(p0s[r]);
            p_lds[wave][g * 4 + r][16 + lo] = (short)bf_rne(p1s[r]);
        }
        asm volatile("s_waitcnt lgkmcnt(0)" ::: "memory");  // per-wave write->read order
        short8 pa = *reinterpret_cast<const short8*>(&p_lds[wave][lo][g * 8]);

        // -------- P @ V from transposed bf16 V: one 16B load per dc --------
        int sb = kb + g * 8;
        if (sb > S_LEN - 8) sb = S_LEN - 8;   // clamp only fires when those P rows are all masked (0)
        #pragma unroll
        for (int dc = 0; dc < 8; ++dc) {
            short8 vb = *reinterpret_cast<const short8*>(
                Vh + (size_t)(dc * 16 + lo) * S_LEN + sb);
            oacc[dc] = __builtin_amdgcn_mfma_f32_16x16x32_bf16(pa, vb, oacc[dc], 0, 0, 0);
        }
    }

    // -------- merge wave1 partial into wave0, write O --------
    if (wave == 1) {
        #pragma unroll
        for (int r = 0; r < 4; ++r) { m_ml[lane][r] = m_r[r]; m_ml[lane][4 + r] = l_r[r]; }
        #pragma unroll
        for (int dc = 0; dc < 8; ++dc)
            *reinterpret_cast<f32x4*>(&m_o[lane][dc * 4]) = oacc[dc];
    }
    __syncthreads();
    if (wave == 0) {
        float sc0[4], sc1[4];
        #pragma unroll
        for (int r = 0; r < 4; ++r) {
            float m1 = m_ml[lane][r], l1 = m_ml[lane][4 + r];
            float mm = fmaxf(m_r[r], m1);
            float e0 = __expf(m_r[r] - mm);
            float e1 = __expf(m1 - mm);
            float inv = 1.f / (l_r[r] * e0 + l1 * e1);
            sc0[r] = e0 * inv; sc1[r] = e1 * inv;
        }
        #pragma unroll
        for (int dc = 0; dc < 8; ++dc) {
            f32x4 o1 = *reinterpret_cast<const f32x4*>(&m_o[lane][dc * 4]);
            #pragma unroll
            for (int r = 0; r < 4; ++r) {
                float val = oacc[dc][r] * sc0[r] + o1[r] * sc1[r];
                Oh[((size_t)(q0 + g * 4 + r) << 7) + dc * 16 + lo] = val;
            }
        }
    }
}

extern "C" void kernel_launch(void* const* d_in, const int* in_sizes, int n_in,
                              void* d_out, int out_size, void* d_ws, size_t ws_size,
                              hipStream_t stream) {
    (void)in_sizes; (void)n_in; (void)out_size; (void)ws_size;
    const float* q = (const float*)d_in[0];
    const float* k = (const float*)d_in[1];
    const float* v = (const float*)d_in[2];
    // d_in[3] = mask: structural (causal sliding window, W=512) — never read.
    float* o = (float*)d_out;

    // workspace: khi | klo | vt  (3 * 8.39 MB = 25.2 MB)
    short* khi = (short*)d_ws;
    short* klo = khi + HSD;
    short* vt  = klo + HSD;

    hipLaunchKernelGGL(split_k, dim3(HSD / 4 / 256), dim3(256), 0, stream, k, khi, klo);
    hipLaunchKernelGGL(vtrans, dim3(S_LEN / 32, D_DIM / 32, H_NUM), dim3(256), 0, stream, v, vt);
    hipLaunchKernelGGL(swa_fwd, dim3(H_NUM * (S_LEN / 16)), dim3(128), 0, stream,
                       q, khi, klo, vt, o);
}

// Round 3
// 84.284 us; speedup vs baseline: 1.4615x; 1.3649x over previous
//
#include <hip/hip_runtime.h>
#include <hip/hip_bf16.h>

#define H_NUM 16
#define S_LEN 2048
#define D_DIM 128
#define WIN   512
#define HSD   (H_NUM * S_LEN * D_DIM)   // 4194304 elements

typedef __attribute__((ext_vector_type(8))) _Float16 half8;
typedef __attribute__((ext_vector_type(4))) _Float16 half4;
typedef __attribute__((ext_vector_type(4))) float f32x4;

// ---- pre-pass 1: K fp32 -> fp16 (11-bit mantissa; QK^T error ~0.005 std) ----
__global__ __launch_bounds__(256) void conv_k(
    const float* __restrict__ K, _Float16* __restrict__ kf)
{
    size_t i = ((size_t)blockIdx.x * 256 + threadIdx.x) * 4;
    float4 x = *reinterpret_cast<const float4*>(K + i);
    half4 h = {(_Float16)x.x, (_Float16)x.y, (_Float16)x.z, (_Float16)x.w};
    *reinterpret_cast<half4*>(kf + i) = h;
}

// ---- pre-pass 2: V [h][s][d] fp32 -> Vt [h][d][s] fp16 (32x32 LDS tiles) ----
__global__ __launch_bounds__(256) void vtrans(
    const float* __restrict__ V, _Float16* __restrict__ vt)
{
    __shared__ _Float16 t[32][33];
    int h = blockIdx.z, s0 = blockIdx.x * 32, d0 = blockIdx.y * 32;
    int tid = threadIdx.x;
    int r = tid >> 3;          // 0..31
    int c = (tid & 7) * 4;     // 0,4,...,28
    float4 x = *reinterpret_cast<const float4*>(
        V + ((size_t)(h * S_LEN + s0 + r) << 7) + d0 + c);
    t[r][c + 0] = (_Float16)x.x;
    t[r][c + 1] = (_Float16)x.y;
    t[r][c + 2] = (_Float16)x.z;
    t[r][c + 3] = (_Float16)x.w;
    __syncthreads();
    half4 y;
    #pragma unroll
    for (int e = 0; e < 4; ++e) y[e] = t[c + e][r];   // Vt[d0+r][s0+c+e] = V[s0+c+e][d0+r]
    *reinterpret_cast<half4*>(vt + (size_t)(h * D_DIM + d0 + r) * S_LEN + s0 + c) = y;
}

// ---- main: flash SWA, 2 waves per WG (KV-split), 16 q-rows per WG ----
// MFMA 16x16x32 f16 layouts (shape-determined, m89/m121-verified):
//   A: row=lane&15, k=(lane>>4)*8+e   B: col=lane&15, k=(lane>>4)*8+e
//   C/D: col=lane&15, row=(lane>>4)*4+reg
__global__ __launch_bounds__(128, 4) void swa_fwd(
    const float* __restrict__ Q, const _Float16* __restrict__ kf,
    const _Float16* __restrict__ vt, float* __restrict__ O)
{
    __shared__ _Float16 p_lds[2][16][40];  // per-wave P redistribution buffer
    __shared__ float m_o[64][36];          // wave1 O-partial (padded)
    __shared__ float m_ml[64][8];          // wave1 m/l partials

    // XCD-bijective swizzle (2048 % 8 == 0): each XCD owns 2 whole heads
    // -> kf16+vt16 working set = 1 MB/head, 2 MB/XCD < 4 MB L2 even with Q/O streams.
    int bid = blockIdx.x;
    int wid = ((bid & 7) << 8) | (bid >> 3);
    int h   = wid >> 7;
    int qt  = wid & 127;
    int q0  = qt << 4;

    int tid  = threadIdx.x;
    int wave = tid >> 6;
    int lane = tid & 63;
    int lo = lane & 15;
    int g  = lane >> 4;

    const float*    Qh = Q  + ((size_t)h << 18);
    const _Float16* Kh = kf + ((size_t)h << 18);
    const _Float16* Vh = vt + ((size_t)h << 18);
    float*          Oh = O  + ((size_t)h << 18);

    // Q fragments -> fp16 (once per wave)
    half8 qa[4];
    const float* qrow = Qh + ((size_t)(q0 + lo) << 7) + g * 8;
    #pragma unroll
    for (int c = 0; c < 4; ++c) {
        float4 a0 = *reinterpret_cast<const float4*>(qrow + c * 32);
        float4 a1 = *reinterpret_cast<const float4*>(qrow + c * 32 + 4);
        qa[c] = (half8){(_Float16)a0.x, (_Float16)a0.y, (_Float16)a0.z, (_Float16)a0.w,
                        (_Float16)a1.x, (_Float16)a1.y, (_Float16)a1.z, (_Float16)a1.w};
    }

    f32x4 oacc[8];
    #pragma unroll
    for (int dc = 0; dc < 8; ++dc) oacc[dc] = (f32x4){0.f, 0.f, 0.f, 0.f};
    float m_r[4], l_r[4];
    #pragma unroll
    for (int r = 0; r < 4; ++r) { m_r[r] = -1e30f; l_r[r] = 0.f; }

    int kstart = q0 - (WIN - 1);
    if (kstart < 0) kstart = 0;
    kstart &= ~31;                      // 32-align (16B-aligned fp16 loads)
    int kend = q0 + 16;
    int nt   = (kend - kstart + 31) >> 5;
    int nt0  = (nt + 1) >> 1;
    int tb = (wave == 0) ? 0   : nt0;
    int te = (wave == 0) ? nt0 : nt;

    for (int ti = tb; ti < te; ++ti) {
        int kb = kstart + ti * 32;

        // -------- K loads: ALL 8 issued before any MFMA (one latency wait/tile) ----
        half8 kh[2][4];
        #pragma unroll
        for (int kg = 0; kg < 2; ++kg) {
            int krow = kb + kg * 16 + lo;
            if (krow > S_LEN - 1) krow = S_LEN - 1;   // masked later
            const _Float16* kp = Kh + ((size_t)krow << 7) + g * 8;
            #pragma unroll
            for (int c = 0; c < 4; ++c)
                kh[kg][c] = *reinterpret_cast<const half8*>(kp + c * 32);
        }

        // -------- QK^T (fp16, single operand) --------
        f32x4 sacc[2];
        sacc[0] = (f32x4){0.f,0.f,0.f,0.f};
        sacc[1] = (f32x4){0.f,0.f,0.f,0.f};
        #pragma unroll
        for (int kg = 0; kg < 2; ++kg)
            #pragma unroll
            for (int c = 0; c < 4; ++c)
                sacc[kg] = __builtin_amdgcn_mfma_f32_16x16x32_f16(qa[c], kh[kg][c], sacc[kg], 0, 0, 0);

        // -------- V loads hoisted: latency hides under softmax --------
        int sb = kb + g * 8;
        if (sb > S_LEN - 8) sb = S_LEN - 8;   // clamp: those P rows are masked (0)
        half8 vb[8];
        #pragma unroll
        for (int dc = 0; dc < 8; ++dc)
            vb[dc] = *reinterpret_cast<const half8*>(
                Vh + (size_t)(dc * 16 + lo) * S_LEN + sb);

        // -------- mask + online softmax (max-reduce only; l deferred) --------
        float p0s[4], p1s[4];
        #pragma unroll
        for (int r = 0; r < 4; ++r) {
            int i_row = q0 + g * 4 + r;
            int j0 = kb + lo, j1 = kb + 16 + lo;
            float s0 = sacc[0][r], s1 = sacc[1][r];
            s0 = ((j0 <= i_row) && (j0 + WIN > i_row)) ? s0 : -1e30f;
            s1 = ((j1 <= i_row) && (j1 + WIN > i_row)) ? s1 : -1e30f;
            float tm = fmaxf(s0, s1);
            tm = fmaxf(tm, __shfl_xor(tm, 1));
            tm = fmaxf(tm, __shfl_xor(tm, 2));
            tm = fmaxf(tm, __shfl_xor(tm, 4));
            tm = fmaxf(tm, __shfl_xor(tm, 8));
            float mn = fmaxf(m_r[r], tm);
            float scale = __expf(m_r[r] - mn);
            float p0 = __expf(s0 - mn);
            float p1 = __expf(s1 - mn);
            l_r[r] = l_r[r] * scale + p0 + p1;   // per-lane partial; reduced in epilogue
            m_r[r] = mn;
            p0s[r] = p0; p1s[r] = p1;
            #pragma unroll
            for (int dc = 0; dc < 8; ++dc) oacc[dc][r] *= scale;
        }

        // -------- P -> LDS (fp16, redistribute to A-fragment layout) --------
        #pragma unroll
        for (int r = 0; r < 4; ++r) {
            p_lds[wave][g * 4 + r][lo]      = (_Float16)p0s[r];
            p_lds[wave][g * 4 + r][16 + lo] = (_Float16)p1s[r];
        }
        asm volatile("s_waitcnt lgkmcnt(0)" ::: "memory");  // per-wave write->read order
        half8 pa = *reinterpret_cast<const half8*>(&p_lds[wave][lo][g * 8]);

        // -------- P @ V (fp16; V already in registers) --------
        #pragma unroll
        for (int dc = 0; dc < 8; ++dc)
            oacc[dc] = __builtin_amdgcn_mfma_f32_16x16x32_f16(pa, vb[dc], oacc[dc], 0, 0, 0);
    }

    // -------- epilogue: reduce deferred l over the 16-lane group --------
    #pragma unroll
    for (int r = 0; r < 4; ++r) {
        float ls = l_r[r];
        ls += __shfl_xor(ls, 1);
        ls += __shfl_xor(ls, 2);
        ls += __shfl_xor(ls, 4);
        ls += __shfl_xor(ls, 8);
        l_r[r] = ls;
    }

    // -------- merge wave1 partial into wave0, write O --------
    if (wave == 1) {
        #pragma unroll
        for (int r = 0; r < 4; ++r) { m_ml[lane][r] = m_r[r]; m_ml[lane][4 + r] = l_r[r]; }
        #pragma unroll
        for (int dc = 0; dc < 8; ++dc)
            *reinterpret_cast<f32x4*>(&m_o[lane][dc * 4]) = oacc[dc];
    }
    __syncthreads();
    if (wave == 0) {
        float sc0[4], sc1[4];
        #pragma unroll
        for (int r = 0; r < 4; ++r) {
            float m1 = m_ml[lane][r], l1 = m_ml[lane][4 + r];
            float mm = fmaxf(m_r[r], m1);
            float e0 = __expf(m_r[r] - mm);
            float e1 = __expf(m1 - mm);
            float inv = 1.f / (l_r[r] * e0 + l1 * e1);
            sc0[r] = e0 * inv; sc1[r] = e1 * inv;
        }
        #pragma unroll
        for (int dc = 0; dc < 8; ++dc) {
            f32x4 o1 = *reinterpret_cast<const f32x4*>(&m_o[lane][dc * 4]);
            #pragma unroll
            for (int r = 0; r < 4; ++r) {
                float val = oacc[dc][r] * sc0[r] + o1[r] * sc1[r];
                Oh[((size_t)(q0 + g * 4 + r) << 7) + dc * 16 + lo] = val;
            }
        }
    }
}

extern "C" void kernel_launch(void* const* d_in, const int* in_sizes, int n_in,
                              void* d_out, int out_size, void* d_ws, size_t ws_size,
                              hipStream_t stream) {
    (void)in_sizes; (void)n_in; (void)out_size; (void)ws_size;
    const float* q = (const float*)d_in[0];
    const float* k = (const float*)d_in[1];
    const float* v = (const float*)d_in[2];
    // d_in[3] = mask: structural (causal sliding window, W=512) — never read.
    float* o = (float*)d_out;

    // workspace: kf16 | vt16  (2 * 8.39 MB = 16.8 MB)
    _Float16* kf = (_Float16*)d_ws;
    _Float16* vt = kf + HSD;

    hipLaunchKernelGGL(conv_k, dim3(HSD / 4 / 256), dim3(256), 0, stream, k, kf);
    hipLaunchKernelGGL(vtrans, dim3(S_LEN / 32, D_DIM / 32, H_NUM), dim3(256), 0, stream, v, vt);
    hipLaunchKernelGGL(swa_fwd, dim3(H_NUM * (S_LEN / 16)), dim3(128), 0, stream,
                       q, kf, vt, o);
}

// Round 4
// 73.075 us; speedup vs baseline: 1.6857x; 1.1534x over previous
//
#include <hip/hip_runtime.h>
#include <hip/hip_bf16.h>

#define H_NUM 16
#define S_LEN 2048
#define D_DIM 128
#define WIN   512
#define HSD   (H_NUM * S_LEN * D_DIM)   // 4194304 elements
// Vt row stride: S_LEN + 8 elements (4112 B). Breaks the exact-4KB power-of-2
// stride that aliased all 16 lanes of the PV gather onto one L1 set / L2
// channel (round-3 latency pathology). Still 16B-aligned (2056 % 8 == 0).
#define VSTRIDE (S_LEN + 8)

typedef __attribute__((ext_vector_type(8))) _Float16 half8;
typedef __attribute__((ext_vector_type(4))) _Float16 half4;
typedef __attribute__((ext_vector_type(4))) float f32x4;

// ---- pre-pass 1: K fp32 -> fp16 (11-bit mantissa; QK^T error ~0.005 std) ----
__global__ __launch_bounds__(256) void conv_k(
    const float* __restrict__ K, _Float16* __restrict__ kf)
{
    size_t i = ((size_t)blockIdx.x * 256 + threadIdx.x) * 4;
    float4 x = *reinterpret_cast<const float4*>(K + i);
    half4 h = {(_Float16)x.x, (_Float16)x.y, (_Float16)x.z, (_Float16)x.w};
    *reinterpret_cast<half4*>(kf + i) = h;
}

// ---- pre-pass 2: V [h][s][d] fp32 -> Vt [h][d][s(padded)] fp16 ----
__global__ __launch_bounds__(256) void vtrans(
    const float* __restrict__ V, _Float16* __restrict__ vt)
{
    __shared__ _Float16 t[32][33];
    int h = blockIdx.z, s0 = blockIdx.x * 32, d0 = blockIdx.y * 32;
    int tid = threadIdx.x;
    int r = tid >> 3;          // 0..31
    int c = (tid & 7) * 4;     // 0,4,...,28
    float4 x = *reinterpret_cast<const float4*>(
        V + ((size_t)(h * S_LEN + s0 + r) << 7) + d0 + c);
    t[r][c + 0] = (_Float16)x.x;
    t[r][c + 1] = (_Float16)x.y;
    t[r][c + 2] = (_Float16)x.z;
    t[r][c + 3] = (_Float16)x.w;
    __syncthreads();
    half4 y;
    #pragma unroll
    for (int e = 0; e < 4; ++e) y[e] = t[c + e][r];   // Vt[d0+r][s0+c+e] = V[s0+c+e][d0+r]
    *reinterpret_cast<half4*>(vt + (size_t)(h * D_DIM + d0 + r) * VSTRIDE + s0 + c) = y;
}

// ---- main: flash SWA, 2 waves per WG (KV-split), 16 q-rows per WG ----
// MFMA 16x16x32 f16 layouts (shape-determined, m89/m121-verified):
//   A: row=lane&15, k=(lane>>4)*8+e   B: col=lane&15, k=(lane>>4)*8+e
//   C/D: col=lane&15, row=(lane>>4)*4+reg
__global__ __launch_bounds__(128, 4) void swa_fwd(
    const float* __restrict__ Q, const _Float16* __restrict__ kf,
    const _Float16* __restrict__ vt, float* __restrict__ O)
{
    __shared__ _Float16 p_lds[2][16][40];  // per-wave P redistribution buffer
    __shared__ float m_o[64][36];          // wave1 O-partial (padded)
    __shared__ float m_ml[64][8];          // wave1 m/l partials

    // XCD-bijective swizzle (2048 % 8 == 0): each XCD owns 2 whole heads
    // -> kf16+vt16 working set ~1 MB/head; 2 MB/XCD stays L2-resident.
    int bid = blockIdx.x;
    int wid = ((bid & 7) << 8) | (bid >> 3);
    int h   = wid >> 7;
    int qt  = wid & 127;
    int q0  = qt << 4;

    int tid  = threadIdx.x;
    int wave = tid >> 6;
    int lane = tid & 63;
    int lo = lane & 15;
    int g  = lane >> 4;

    const float*    Qh = Q  + ((size_t)h << 18);
    const _Float16* Kh = kf + ((size_t)h << 18);
    const _Float16* Vh = vt + (size_t)h * D_DIM * VSTRIDE;
    float*          Oh = O  + ((size_t)h << 18);

    // Q fragments -> fp16 (once per wave)
    half8 qa[4];
    const float* qrow = Qh + ((size_t)(q0 + lo) << 7) + g * 8;
    #pragma unroll
    for (int c = 0; c < 4; ++c) {
        float4 a0 = *reinterpret_cast<const float4*>(qrow + c * 32);
        float4 a1 = *reinterpret_cast<const float4*>(qrow + c * 32 + 4);
        qa[c] = (half8){(_Float16)a0.x, (_Float16)a0.y, (_Float16)a0.z, (_Float16)a0.w,
                        (_Float16)a1.x, (_Float16)a1.y, (_Float16)a1.z, (_Float16)a1.w};
    }

    f32x4 oacc[8];
    #pragma unroll
    for (int dc = 0; dc < 8; ++dc) oacc[dc] = (f32x4){0.f, 0.f, 0.f, 0.f};
    float m_r[4], l_r[4];
    #pragma unroll
    for (int r = 0; r < 4; ++r) { m_r[r] = -1e30f; l_r[r] = 0.f; }

    int kstart = q0 - (WIN - 1);
    if (kstart < 0) kstart = 0;
    kstart &= ~31;                      // 32-align (16B-aligned fp16 loads)
    int kend = q0 + 16;
    int nt   = (kend - kstart + 31) >> 5;
    int nt0  = (nt + 1) >> 1;
    int tb = (wave == 0) ? 0   : nt0;
    int te = (wave == 0) ? nt0 : nt;

    for (int ti = tb; ti < te; ++ti) {
        int kb = kstart + ti * 32;

        // -------- K loads: ALL 8 issued before any MFMA (one latency wait/tile) ----
        half8 kh[2][4];
        #pragma unroll
        for (int kg = 0; kg < 2; ++kg) {
            int krow = kb + kg * 16 + lo;
            if (krow > S_LEN - 1) krow = S_LEN - 1;   // masked later
            const _Float16* kp = Kh + ((size_t)krow << 7) + g * 8;
            #pragma unroll
            for (int c = 0; c < 4; ++c)
                kh[kg][c] = *reinterpret_cast<const half8*>(kp + c * 32);
        }

        // -------- QK^T (fp16, single operand) --------
        f32x4 sacc[2];
        sacc[0] = (f32x4){0.f,0.f,0.f,0.f};
        sacc[1] = (f32x4){0.f,0.f,0.f,0.f};
        #pragma unroll
        for (int kg = 0; kg < 2; ++kg)
            #pragma unroll
            for (int c = 0; c < 4; ++c)
                sacc[kg] = __builtin_amdgcn_mfma_f32_16x16x32_f16(qa[c], kh[kg][c], sacc[kg], 0, 0, 0);

        // -------- V loads hoisted: latency hides under softmax --------
        int sb = kb + g * 8;
        if (sb > S_LEN - 8) sb = S_LEN - 8;   // clamp: those P rows are masked (0)
        half8 vb[8];
        #pragma unroll
        for (int dc = 0; dc < 8; ++dc)
            vb[dc] = *reinterpret_cast<const half8*>(
                Vh + (size_t)(dc * 16 + lo) * VSTRIDE + sb);

        // -------- mask + online softmax (max-reduce only; l deferred) --------
        float p0s[4], p1s[4];
        #pragma unroll
        for (int r = 0; r < 4; ++r) {
            int i_row = q0 + g * 4 + r;
            int j0 = kb + lo, j1 = kb + 16 + lo;
            float s0 = sacc[0][r], s1 = sacc[1][r];
            s0 = ((j0 <= i_row) && (j0 + WIN > i_row)) ? s0 : -1e30f;
            s1 = ((j1 <= i_row) && (j1 + WIN > i_row)) ? s1 : -1e30f;
            float tm = fmaxf(s0, s1);
            tm = fmaxf(tm, __shfl_xor(tm, 1));
            tm = fmaxf(tm, __shfl_xor(tm, 2));
            tm = fmaxf(tm, __shfl_xor(tm, 4));
            tm = fmaxf(tm, __shfl_xor(tm, 8));
            float mn = fmaxf(m_r[r], tm);
            float scale = __expf(m_r[r] - mn);
            float p0 = __expf(s0 - mn);
            float p1 = __expf(s1 - mn);
            l_r[r] = l_r[r] * scale + p0 + p1;   // per-lane partial; reduced in epilogue
            m_r[r] = mn;
            p0s[r] = p0; p1s[r] = p1;
            #pragma unroll
            for (int dc = 0; dc < 8; ++dc) oacc[dc][r] *= scale;
        }

        // -------- P -> LDS (fp16, redistribute to A-fragment layout) --------
        #pragma unroll
        for (int r = 0; r < 4; ++r) {
            p_lds[wave][g * 4 + r][lo]      = (_Float16)p0s[r];
            p_lds[wave][g * 4 + r][16 + lo] = (_Float16)p1s[r];
        }
        asm volatile("s_waitcnt lgkmcnt(0)" ::: "memory");  // per-wave write->read order
        half8 pa = *reinterpret_cast<const half8*>(&p_lds[wave][lo][g * 8]);

        // -------- P @ V (fp16; V already in registers) --------
        #pragma unroll
        for (int dc = 0; dc < 8; ++dc)
            oacc[dc] = __builtin_amdgcn_mfma_f32_16x16x32_f16(pa, vb[dc], oacc[dc], 0, 0, 0);
    }

    // -------- epilogue: reduce deferred l over the 16-lane group --------
    #pragma unroll
    for (int r = 0; r < 4; ++r) {
        float ls = l_r[r];
        ls += __shfl_xor(ls, 1);
        ls += __shfl_xor(ls, 2);
        ls += __shfl_xor(ls, 4);
        ls += __shfl_xor(ls, 8);
        l_r[r] = ls;
    }

    // -------- merge wave1 partial into wave0, write O --------
    if (wave == 1) {
        #pragma unroll
        for (int r = 0; r < 4; ++r) { m_ml[lane][r] = m_r[r]; m_ml[lane][4 + r] = l_r[r]; }
        #pragma unroll
        for (int dc = 0; dc < 8; ++dc)
            *reinterpret_cast<f32x4*>(&m_o[lane][dc * 4]) = oacc[dc];
    }
    __syncthreads();
    if (wave == 0) {
        float sc0[4], sc1[4];
        #pragma unroll
        for (int r = 0; r < 4; ++r) {
            float m1 = m_ml[lane][r], l1 = m_ml[lane][4 + r];
            float mm = fmaxf(m_r[r], m1);
            float e0 = __expf(m_r[r] - mm);
            float e1 = __expf(m1 - mm);
            float inv = 1.f / (l_r[r] * e0 + l1 * e1);
            sc0[r] = e0 * inv; sc1[r] = e1 * inv;
        }
        #pragma unroll
        for (int dc = 0; dc < 8; ++dc) {
            f32x4 o1 = *reinterpret_cast<const f32x4*>(&m_o[lane][dc * 4]);
            #pragma unroll
            for (int r = 0; r < 4; ++r) {
                float val = oacc[dc][r] * sc0[r] + o1[r] * sc1[r];
                Oh[((size_t)(q0 + g * 4 + r) << 7) + dc * 16 + lo] = val;
            }
        }
    }
}

extern "C" void kernel_launch(void* const* d_in, const int* in_sizes, int n_in,
                              void* d_out, int out_size, void* d_ws, size_t ws_size,
                              hipStream_t stream) {
    (void)in_sizes; (void)n_in; (void)out_size; (void)ws_size;
    const float* q = (const float*)d_in[0];
    const float* k = (const float*)d_in[1];
    const float* v = (const float*)d_in[2];
    // d_in[3] = mask: structural (causal sliding window, W=512) — never read.
    float* o = (float*)d_out;

    // workspace: kf16 | vt16(padded)  (8.39 MB + 8.42 MB = 16.8 MB)
    _Float16* kf = (_Float16*)d_ws;
    _Float16* vt = kf + HSD;

    hipLaunchKernelGGL(conv_k, dim3(HSD / 4 / 256), dim3(256), 0, stream, k, kf);
    hipLaunchKernelGGL(vtrans, dim3(S_LEN / 32, D_DIM / 32, H_NUM), dim3(256), 0, stream, v, vt);
    hipLaunchKernelGGL(swa_fwd, dim3(H_NUM * (S_LEN / 16)), dim3(128), 0, stream,
                       q, kf, vt, o);
}

// Round 5
// 57.334 us; speedup vs baseline: 2.1485x; 1.2746x over previous
//
#include <hip/hip_runtime.h>
#include <hip/hip_bf16.h>
#include <stdint.h>

#define H_NUM 16
#define S_LEN 2048
#define D_DIM 128
#define WIN   512
#define HSD   (H_NUM * S_LEN * D_DIM)   // 4194304 elements
#define VSTRIDE (S_LEN + 8)             // padded Vt row stride (r4 fix, kept)
#define QB    64                        // q-rows per WG (4 waves x 16)
#define NWG   (H_NUM * S_LEN / QB)      // 512 WGs

typedef __attribute__((ext_vector_type(8))) _Float16 half8;
typedef __attribute__((ext_vector_type(4))) _Float16 half4;
typedef __attribute__((ext_vector_type(4))) float f32x4;

// async global->LDS, 16B per lane: HW writes wave-uniform LDS base + lane*16;
// global src is per-lane (carries the inverse swizzle, G21 pattern).
static __device__ __forceinline__ void gload16(const void* g, void* l) {
    __builtin_amdgcn_global_load_lds(
        (const __attribute__((address_space(1))) uint32_t*)g,
        (__attribute__((address_space(3))) uint32_t*)l, 16, 0, 0);
}

// ---- pre-pass 1: K fp32 -> fp16 row-major ----
__global__ __launch_bounds__(256) void conv_k(
    const float* __restrict__ K, _Float16* __restrict__ kf)
{
    size_t i = ((size_t)blockIdx.x * 256 + threadIdx.x) * 4;
    float4 x = *reinterpret_cast<const float4*>(K + i);
    half4 h = {(_Float16)x.x, (_Float16)x.y, (_Float16)x.z, (_Float16)x.w};
    *reinterpret_cast<half4*>(kf + i) = h;
}

// ---- pre-pass 2: V [h][s][d] fp32 -> Vt [h][d][s pad] fp16 ----
__global__ __launch_bounds__(256) void vtrans(
    const float* __restrict__ V, _Float16* __restrict__ vt)
{
    __shared__ _Float16 t[32][33];
    int h = blockIdx.z, s0 = blockIdx.x * 32, d0 = blockIdx.y * 32;
    int tid = threadIdx.x;
    int r = tid >> 3;
    int c = (tid & 7) * 4;
    float4 x = *reinterpret_cast<const float4*>(
        V + ((size_t)(h * S_LEN + s0 + r) << 7) + d0 + c);
    t[r][c + 0] = (_Float16)x.x;
    t[r][c + 1] = (_Float16)x.y;
    t[r][c + 2] = (_Float16)x.z;
    t[r][c + 3] = (_Float16)x.w;
    __syncthreads();
    half4 y;
    #pragma unroll
    for (int e = 0; e < 4; ++e) y[e] = t[c + e][r];
    *reinterpret_cast<half4*>(vt + (size_t)(h * D_DIM + d0 + r) * VSTRIDE + s0 + c) = y;
}

// ---- main: 4 waves/WG, 4 consecutive q-tiles, shared dbuf-LDS KV pipeline ----
// MFMA 16x16x32 f16 layouts (m89/m121-verified):
//   A: row=lane&15, k=(lane>>4)*8+e   B: col=lane&15, k=(lane>>4)*8+e
//   C/D: col=lane&15, row=(lane>>4)*4+reg
// K LDS tile: [32 key][256B], byte = row*256 + (col ^ ((row&7)<<4))   [m214 swizzle]
// V LDS tile: [128 d][64B],   byte = row*64  + (col ^ ((row&3)<<4))
__global__ __launch_bounds__(256) void swa_fwd(
    const float* __restrict__ Q, const _Float16* __restrict__ kf,
    const _Float16* __restrict__ vt, float* __restrict__ O)
{
    __shared__ __align__(16) char ks[2][32 * 256];
    __shared__ __align__(16) char vs[2][128 * 64];
    __shared__ _Float16 p_lds[4][16][40];

    // XCD-bijective swizzle (512 % 8 == 0): each XCD owns 2 whole heads (2 MB L2 set).
    int bid = blockIdx.x;
    int wid = ((bid & 7) << 6) | (bid >> 3);
    int h    = wid >> 5;
    int qtg  = wid & 31;
    int q0wg = qtg << 6;

    int tid  = threadIdx.x;
    int wv   = tid >> 6;
    int lane = tid & 63;
    int lo = lane & 15;
    int g  = lane >> 4;
    int q0 = q0wg + wv * 16;          // this wave's 16 q-rows

    const float* Qh = Q + ((size_t)h << 18);
    const char*  Kb = (const char*)(kf + ((size_t)h << 18));
    const char*  Vb = (const char*)(vt + (size_t)h * D_DIM * VSTRIDE);
    float*       Oh = O + ((size_t)h << 18);

    // Q fragments -> fp16 (once per wave)
    half8 qa[4];
    const float* qrow = Qh + ((size_t)(q0 + lo) << 7) + g * 8;
    #pragma unroll
    for (int c = 0; c < 4; ++c) {
        float4 a0 = *reinterpret_cast<const float4*>(qrow + c * 32);
        float4 a1 = *reinterpret_cast<const float4*>(qrow + c * 32 + 4);
        qa[c] = (half8){(_Float16)a0.x, (_Float16)a0.y, (_Float16)a0.z, (_Float16)a0.w,
                        (_Float16)a1.x, (_Float16)a1.y, (_Float16)a1.z, (_Float16)a1.w};
    }

    f32x4 oacc[8];
    #pragma unroll
    for (int dc = 0; dc < 8; ++dc) oacc[dc] = (f32x4){0.f, 0.f, 0.f, 0.f};
    float m_r[4], l_r[4];
    #pragma unroll
    for (int r = 0; r < 4; ++r) { m_r[r] = -1e30f; l_r[r] = 0.f; }

    int kstart = q0wg - (WIN - 1);
    if (kstart < 0) kstart = 0;
    kstart &= ~31;                       // 32-aligned; kend is 64-aligned
    int nt   = ((q0wg + QB) - kstart) >> 5;
    int w_ks = q0 - (WIN - 1);           // this wave's window (signed)
    int w_ke = q0 + 16;

    // Stage tile KB into buf: 8 K-issues + 8 V-issues split across 4 waves (2+2 each).
    // LDS dest is linear (wave-uniform base, HW adds lane*16); global src carries
    // the inverse XOR so the read-side swizzle decodes correctly (G21).
#define STAGE(BUF, KB)                                                          \
    do {                                                                        \
        _Pragma("unroll")                                                       \
        for (int i = 0; i < 2; ++i) {                                           \
            int slot = (wv * 2 + i) * 1024 + lane * 16;                         \
            int krow = slot >> 8;                                               \
            int kcol = (slot & 255) ^ ((krow & 7) << 4);                        \
            gload16(Kb + (((size_t)((KB) + krow)) << 8) + kcol,                 \
                    &ks[BUF][(wv * 2 + i) * 1024]);                             \
            int vrow = slot >> 6;                                               \
            int vcol = (slot & 63) ^ ((vrow & 3) << 4);                         \
            gload16(Vb + (size_t)vrow * (VSTRIDE * 2) + (size_t)(KB) * 2 + vcol,\
                    &vs[BUF][(wv * 2 + i) * 1024]);                             \
        }                                                                       \
    } while (0)

    STAGE(0, kstart);
    __syncthreads();                     // drains vmcnt: tile 0 resident

    for (int t = 0; t < nt; ++t) {
        int kb  = kstart + t * 32;
        int cur = t & 1;
        if (t + 1 < nt) STAGE(cur ^ 1, kb + 32);   // async prefetch

        bool act = (kb < w_ke) && (kb + 32 > w_ks);   // wave-uniform
        if (act) {
            const char* ksb = ks[cur];
            const char* vsb = vs[cur];

            // -------- QK^T from LDS (swizzled ds_read_b128) --------
            f32x4 sacc[2];
            sacc[0] = (f32x4){0.f,0.f,0.f,0.f};
            sacc[1] = (f32x4){0.f,0.f,0.f,0.f};
            #pragma unroll
            for (int kg = 0; kg < 2; ++kg) {
                int krow = kg * 16 + lo;
                int sw = (krow & 7) << 4;
                #pragma unroll
                for (int c = 0; c < 4; ++c) {
                    half8 kh = *reinterpret_cast<const half8*>(
                        ksb + krow * 256 + ((c * 64 + g * 16) ^ sw));
                    sacc[kg] = __builtin_amdgcn_mfma_f32_16x16x32_f16(qa[c], kh, sacc[kg], 0, 0, 0);
                }
            }

            // -------- mask + online softmax (l deferred to epilogue) --------
            float p0s[4], p1s[4];
            #pragma unroll
            for (int r = 0; r < 4; ++r) {
                int i_row = q0 + g * 4 + r;
                int j0 = kb + lo, j1 = kb + 16 + lo;
                float s0 = sacc[0][r], s1 = sacc[1][r];
                s0 = ((j0 <= i_row) && (j0 + WIN > i_row)) ? s0 : -1e30f;
                s1 = ((j1 <= i_row) && (j1 + WIN > i_row)) ? s1 : -1e30f;
                float tm = fmaxf(s0, s1);
                tm = fmaxf(tm, __shfl_xor(tm, 1));
                tm = fmaxf(tm, __shfl_xor(tm, 2));
                tm = fmaxf(tm, __shfl_xor(tm, 4));
                tm = fmaxf(tm, __shfl_xor(tm, 8));
                float mn = fmaxf(m_r[r], tm);
                float scale = __expf(m_r[r] - mn);
                float p0 = __expf(s0 - mn);
                float p1 = __expf(s1 - mn);
                l_r[r] = l_r[r] * scale + p0 + p1;
                m_r[r] = mn;
                p0s[r] = p0; p1s[r] = p1;
                #pragma unroll
                for (int dc = 0; dc < 8; ++dc) oacc[dc][r] *= scale;
            }

            // -------- P -> LDS (redistribute to A-fragment layout) --------
            #pragma unroll
            for (int r = 0; r < 4; ++r) {
                p_lds[wv][g * 4 + r][lo]      = (_Float16)p0s[r];
                p_lds[wv][g * 4 + r][16 + lo] = (_Float16)p1s[r];
            }
            asm volatile("s_waitcnt lgkmcnt(0)" ::: "memory");
            half8 pa = *reinterpret_cast<const half8*>(&p_lds[wv][lo][g * 8]);

            // -------- P @ V from LDS --------
            #pragma unroll
            for (int dc = 0; dc < 8; ++dc) {
                int vrow = dc * 16 + lo;
                half8 vb8 = *reinterpret_cast<const half8*>(
                    vsb + vrow * 64 + ((g * 16) ^ ((vrow & 3) << 4)));
                oacc[dc] = __builtin_amdgcn_mfma_f32_16x16x32_f16(pa, vb8, oacc[dc], 0, 0, 0);
            }
        }
        __syncthreads();   // drains this wave's stage loads + all buf[cur] reads
    }

    // -------- epilogue: reduce deferred l, normalize, store --------
    #pragma unroll
    for (int r = 0; r < 4; ++r) {
        float ls = l_r[r];
        ls += __shfl_xor(ls, 1);
        ls += __shfl_xor(ls, 2);
        ls += __shfl_xor(ls, 4);
        ls += __shfl_xor(ls, 8);
        float inv = 1.0f / ls;
        float* orow = Oh + ((size_t)(q0 + g * 4 + r) << 7) + lo;
        #pragma unroll
        for (int dc = 0; dc < 8; ++dc)
            orow[dc * 16] = oacc[dc][r] * inv;
    }
#undef STAGE
}

extern "C" void kernel_launch(void* const* d_in, const int* in_sizes, int n_in,
                              void* d_out, int out_size, void* d_ws, size_t ws_size,
                              hipStream_t stream) {
    (void)in_sizes; (void)n_in; (void)out_size; (void)ws_size;
    const float* q = (const float*)d_in[0];
    const float* k = (const float*)d_in[1];
    const float* v = (const float*)d_in[2];
    // d_in[3] = mask: structural (causal sliding window, W=512) — never read.
    float* o = (float*)d_out;

    // workspace: kf16 | vt16(padded)
    _Float16* kf = (_Float16*)d_ws;
    _Float16* vt = kf + HSD;

    hipLaunchKernelGGL(conv_k, dim3(HSD / 4 / 256), dim3(256), 0, stream, k, kf);
    hipLaunchKernelGGL(vtrans, dim3(S_LEN / 32, D_DIM / 32, H_NUM), dim3(256), 0, stream, v, vt);
    hipLaunchKernelGGL(swa_fwd, dim3(NWG), dim3(256), 0, stream, q, kf, vt, o);
}

// Round 6
// 44.479 us; speedup vs baseline: 2.7695x; 1.2890x over previous
//
#include <hip/hip_runtime.h>
#include <hip/hip_bf16.h>
#include <stdint.h>

#define H_NUM 16
#define S_LEN 2048
#define D_DIM 128
#define WIN   512
#define HSD   (H_NUM * S_LEN * D_DIM)   // 4194304 elements
#define VSTRIDE (S_LEN + 8)             // padded Vt row stride (r4 fix)
#define QB    64                        // q-rows per WG (4 q-tiles)
#define NWG   (H_NUM * S_LEN / QB)      // 512 WGs x 512 threads = 4096 waves

typedef __attribute__((ext_vector_type(8))) _Float16 half8;
typedef __attribute__((ext_vector_type(4))) _Float16 half4;
typedef __attribute__((ext_vector_type(4))) float f32x4;

static __device__ __forceinline__ void gload16(const void* g, void* l) {
    __builtin_amdgcn_global_load_lds(
        (const __attribute__((address_space(1))) uint32_t*)g,
        (__attribute__((address_space(3))) uint32_t*)l, 16, 0, 0);
}

// ---- pre-pass 1: K fp32 -> fp16 row-major ----
__global__ __launch_bounds__(256) void conv_k(
    const float* __restrict__ K, _Float16* __restrict__ kf)
{
    size_t i = ((size_t)blockIdx.x * 256 + threadIdx.x) * 4;
    float4 x = *reinterpret_cast<const float4*>(K + i);
    half4 h = {(_Float16)x.x, (_Float16)x.y, (_Float16)x.z, (_Float16)x.w};
    *reinterpret_cast<half4*>(kf + i) = h;
}

// ---- pre-pass 2: V [h][s][d] fp32 -> Vt [h][d][s pad] fp16 ----
__global__ __launch_bounds__(256) void vtrans(
    const float* __restrict__ V, _Float16* __restrict__ vt)
{
    __shared__ _Float16 t[32][33];
    int h = blockIdx.z, s0 = blockIdx.x * 32, d0 = blockIdx.y * 32;
    int tid = threadIdx.x;
    int r = tid >> 3;
    int c = (tid & 7) * 4;
    float4 x = *reinterpret_cast<const float4*>(
        V + ((size_t)(h * S_LEN + s0 + r) << 7) + d0 + c);
    t[r][c + 0] = (_Float16)x.x;
    t[r][c + 1] = (_Float16)x.y;
    t[r][c + 2] = (_Float16)x.z;
    t[r][c + 3] = (_Float16)x.w;
    __syncthreads();
    half4 y;
    #pragma unroll
    for (int e = 0; e < 4; ++e) y[e] = t[c + e][r];
    *reinterpret_cast<half4*>(vt + (size_t)(h * D_DIM + d0 + r) * VSTRIDE + s0 + c) = y;
}

// ---- main: 8 waves/WG = 4 q-tiles x 2 window-halves; dual-stream LDS dbuf ----
// Swapped QK^T: A=K, B=Q -> D[key][q]: col=lane&15=q, row=(lane>>4)*4+reg=key.
// A/B frag lane-maps identical (row|col=lane&15, k=(lane>>4)*8+e) so K/Q loads
// are unchanged from r5. PV unchanged: D[q][d], col=lane&15=d, row=g*4+r=q.
__global__ __launch_bounds__(512, 4) void swa_fwd(
    const float* __restrict__ Q, const _Float16* __restrict__ kf,
    const _Float16* __restrict__ vt, float* __restrict__ O)
{
    // 75776 B arena: staging + p_lds; merge aliases dead staging post-loop.
    __shared__ __align__(16) char arena[75776];
    char* ksL = arena;                         // [2][8192] K low-stream
    char* vsL = arena + 16384;                 // [2][8192] V low-stream
    char* ksH = arena + 32768;                 // [2][8192] K high-stream
    char* vsH = arena + 49152;                 // [2][8192] V high-stream
    _Float16* p_lds = (_Float16*)(arena + 65536);  // [8][16][40]
    float* mrg_o  = (float*)(arena + 32768);   // [4][64][36]  (post-loop)
    float* mrg_ml = (float*)(arena + 69632);   // [4][64][2]   (post-loop)

    // XCD-bijective swizzle (512 % 8 == 0)
    int bid = blockIdx.x;
    int wid = ((bid & 7) << 6) | (bid >> 3);
    int h    = wid >> 5;
    int q0wg = (wid & 31) << 6;

    int tid  = threadIdx.x;
    int wv   = tid >> 6;
    int lane = tid & 63;
    int lo = lane & 15;
    int g  = lane >> 4;
    int qsel = wv & 3;          // which q-tile
    int hseg = wv >> 2;         // 0 = low window half, 1 = high half
    int q0 = q0wg + qsel * 16;

    const float*    Qh = Q  + ((size_t)h << 18);
    const char*     Kb = (const char*)(kf + ((size_t)h << 18));
    const char*     Vb = (const char*)(vt + (size_t)h * D_DIM * VSTRIDE);
    float*          Oh = O  + ((size_t)h << 18);

    // Q fragments -> fp16 (B operand; lane holds Q[q=lo][d=c*32+g*8..+7])
    half8 qa[4];
    const float* qrow = Qh + ((size_t)(q0 + lo) << 7) + g * 8;
    #pragma unroll
    for (int c = 0; c < 4; ++c) {
        float4 a0 = *reinterpret_cast<const float4*>(qrow + c * 32);
        float4 a1 = *reinterpret_cast<const float4*>(qrow + c * 32 + 4);
        qa[c] = (half8){(_Float16)a0.x, (_Float16)a0.y, (_Float16)a0.z, (_Float16)a0.w,
                        (_Float16)a1.x, (_Float16)a1.y, (_Float16)a1.z, (_Float16)a1.w};
    }

    f32x4 oacc[8];
    #pragma unroll
    for (int dc = 0; dc < 8; ++dc) oacc[dc] = (f32x4){0.f, 0.f, 0.f, 0.f};
    float m_s = -1e30f, l_s = 0.f;   // per-lane online stats for q = q0+lo

    int kstart = q0wg - (WIN - 1);
    if (kstart < 0) kstart = 0;
    kstart &= ~31;
    int nt  = ((q0wg + QB) - kstart) >> 5;   // total 32-key tiles (>=2)
    int nt0 = (nt + 1) >> 1;                 // low-stream tiles
    int ntH = nt - nt0;                      // high-stream tiles (>=1)
    int iq   = q0 + lo;                      // this lane's q row
    int w_ks = q0 - (WIN - 1);
    int w_ke = q0 + 16;

    // Stage one 1KB K-slot + one 1KB V-slot per wave into a stream buffer.
    // LDS dest wave-uniform (HW adds lane*16); global src carries inverse XOR.
#define STAGE1(KS, VS, BUF, KB_) do {                                          \
        int sb_  = wv * 1024 + lane * 16;                                      \
        int kr_  = sb_ >> 8;                                                   \
        int kc_  = (sb_ & 255) ^ ((kr_ & 7) << 4);                             \
        gload16(Kb + (((size_t)((KB_) + kr_)) << 8) + kc_,                     \
                (KS) + (BUF) * 8192 + wv * 1024);                              \
        int vr_  = sb_ >> 6;                                                   \
        int vc_  = (sb_ & 63) ^ ((vr_ & 3) << 4);                              \
        gload16(Vb + (size_t)vr_ * (VSTRIDE * 2) + (size_t)(KB_) * 2 + vc_,    \
                (VS) + (BUF) * 8192 + wv * 1024);                              \
    } while (0)

    STAGE1(ksL, vsL, 0, kstart);
    STAGE1(ksH, vsH, 0, kstart + nt0 * 32);
    __syncthreads();

    int my_cnt = hseg ? ntH : nt0;
    for (int it = 0; it < nt0; ++it) {
        int cur = it & 1;
        if (it + 1 < nt0) STAGE1(ksL, vsL, cur ^ 1, kstart + (it + 1) * 32);
        if (it + 1 < ntH) STAGE1(ksH, vsH, cur ^ 1, kstart + (nt0 + it + 1) * 32);

        int mt = (hseg ? nt0 : 0) + it;
        int kb = kstart + mt * 32;
        bool act = (it < my_cnt) && (kb < w_ke) && (kb + 32 > w_ks);
        if (act) {
            const char* ksb = (hseg ? ksH : ksL) + cur * 8192;
            const char* vsb = (hseg ? vsH : vsL) + cur * 8192;

            // -------- QK^T swapped (A=K, B=Q): D[key][q] --------
            f32x4 sacc[2];
            sacc[0] = (f32x4){0.f,0.f,0.f,0.f};
            sacc[1] = (f32x4){0.f,0.f,0.f,0.f};
            #pragma unroll
            for (int kg = 0; kg < 2; ++kg) {
                int krow = kg * 16 + lo;
                int sw = (krow & 7) << 4;
                #pragma unroll
                for (int c = 0; c < 4; ++c) {
                    half8 kh = *reinterpret_cast<const half8*>(
                        ksb + krow * 256 + ((c * 64 + g * 16) ^ sw));
                    sacc[kg] = __builtin_amdgcn_mfma_f32_16x16x32_f16(kh, qa[c], sacc[kg], 0, 0, 0);
                }
            }

            // -------- in-register softmax: lane owns 8 scores of row q=lo ----
            float s8[8];
            float tm = -1e30f;
            #pragma unroll
            for (int kg = 0; kg < 2; ++kg)
                #pragma unroll
                for (int r = 0; r < 4; ++r) {
                    int j = kb + kg * 16 + g * 4 + r;
                    float s = sacc[kg][r];
                    s = ((j <= iq) && (j + WIN > iq)) ? s : -1e30f;
                    s8[kg * 4 + r] = s;
                    tm = fmaxf(tm, s);
                }
            tm = fmaxf(tm, __shfl_xor(tm, 16));
            tm = fmaxf(tm, __shfl_xor(tm, 32));   // full 32-key row max
            float mn = fmaxf(m_s, tm);
            float scale = __expf(m_s - mn);
            m_s = mn;
            float ps = 0.f;
            _Float16 pf[8];
            #pragma unroll
            for (int i = 0; i < 8; ++i) {
                float p = __expf(s8[i] - mn);
                ps += p;
                pf[i] = (_Float16)p;
            }
            l_s = l_s * scale + ps;   // per-lane partial (4 copies per q-row)

            // -------- P scatter: p_lds[wv][q=lo][j] --------
            _Float16* pw = p_lds + wv * 640 + lo * 40;
            #pragma unroll
            for (int kg = 0; kg < 2; ++kg)
                #pragma unroll
                for (int r = 0; r < 4; ++r)
                    pw[kg * 16 + g * 4 + r] = pf[kg * 4 + r];

            // -------- rescale O (rows q = g*4+r; scale lives at lane lo=q) ----
            float sc[4];
            #pragma unroll
            for (int r = 0; r < 4; ++r) sc[r] = __shfl(scale, g * 4 + r);
            #pragma unroll
            for (int dc = 0; dc < 8; ++dc)
                #pragma unroll
                for (int r = 0; r < 4; ++r) oacc[dc][r] *= sc[r];

            asm volatile("s_waitcnt lgkmcnt(0)" ::: "memory");
            half8 pa = *reinterpret_cast<const half8*>(p_lds + wv * 640 + lo * 40 + g * 8);

            // -------- P @ V --------
            #pragma unroll
            for (int dc = 0; dc < 8; ++dc) {
                int vrow = dc * 16 + lo;
                half8 vb8 = *reinterpret_cast<const half8*>(
                    vsb + vrow * 64 + ((g * 16) ^ ((vrow & 3) << 4)));
                oacc[dc] = __builtin_amdgcn_mfma_f32_16x16x32_f16(pa, vb8, oacc[dc], 0, 0, 0);
            }
        }
        __syncthreads();
    }

    // -------- epilogue: finish l (sum the 4 per-lane copies) --------
    l_s += __shfl_xor(l_s, 16);
    l_s += __shfl_xor(l_s, 32);

    // -------- merge halves (arena aliases dead staging LDS) --------
    if (hseg == 1) {
        float* ob = mrg_o + (size_t)(qsel * 64 + lane) * 36;
        #pragma unroll
        for (int dc = 0; dc < 8; ++dc)
            *reinterpret_cast<f32x4*>(ob + dc * 4) = oacc[dc];
        mrg_ml[(qsel * 64 + lane) * 2 + 0] = m_s;
        mrg_ml[(qsel * 64 + lane) * 2 + 1] = l_s;
    }
    __syncthreads();
    if (hseg == 0) {
        float m1 = mrg_ml[(qsel * 64 + lane) * 2 + 0];
        float l1 = mrg_ml[(qsel * 64 + lane) * 2 + 1];
        float mm = fmaxf(m_s, m1);
        float e0 = __expf(m_s - mm);
        float e1 = __expf(m1 - mm);
        float inv = 1.f / (l_s * e0 + l1 * e1);
        float sc0 = e0 * inv, sc1 = e1 * inv;
        float s0r[4], s1r[4];
        #pragma unroll
        for (int r = 0; r < 4; ++r) {
            s0r[r] = __shfl(sc0, g * 4 + r);
            s1r[r] = __shfl(sc1, g * 4 + r);
        }
        const float* ob = mrg_o + (size_t)(qsel * 64 + lane) * 36;
        #pragma unroll
        for (int dc = 0; dc < 8; ++dc) {
            f32x4 o1 = *reinterpret_cast<const f32x4*>(ob + dc * 4);
            #pragma unroll
            for (int r = 0; r < 4; ++r) {
                float val = oacc[dc][r] * s0r[r] + o1[r] * s1r[r];
                Oh[((size_t)(q0 + g * 4 + r) << 7) + dc * 16 + lo] = val;
            }
        }
    }
#undef STAGE1
}

extern "C" void kernel_launch(void* const* d_in, const int* in_sizes, int n_in,
                              void* d_out, int out_size, void* d_ws, size_t ws_size,
                              hipStream_t stream) {
    (void)in_sizes; (void)n_in; (void)out_size; (void)ws_size;
    const float* q = (const float*)d_in[0];
    const float* k = (const float*)d_in[1];
    const float* v = (const float*)d_in[2];
    // d_in[3] = mask: structural (causal sliding window, W=512) — never read.
    float* o = (float*)d_out;

    _Float16* kf = (_Float16*)d_ws;
    _Float16* vt = kf + HSD;

    hipLaunchKernelGGL(conv_k, dim3(HSD / 4 / 256), dim3(256), 0, stream, k, kf);
    hipLaunchKernelGGL(vtrans, dim3(S_LEN / 32, D_DIM / 32, H_NUM), dim3(256), 0, stream, v, vt);
    hipLaunchKernelGGL(swa_fwd, dim3(NWG), dim3(512), 0, stream, q, kf, vt, o);
}